// Round 12
// baseline (197.232 us; speedup 1.0000x reference)
//
#include <hip/hip_runtime.h>
#include <hip/hip_fp16.h>

typedef unsigned long long u64;
typedef unsigned int uint32;
typedef short short8 __attribute__((ext_vector_type(8)));
typedef float f32x4 __attribute__((ext_vector_type(4)));
typedef _Float16 h2 __attribute__((ext_vector_type(2)));

#define B_N 8192
#define L_N 1024
#define M_N 128
#define C_N 16         // chunks over L
#define CH_N 64        // steps per chunk
#define HALF_N 512

// ws layout (bytes)
#define OFF_W16  0           // w16[i][m] fp16: 256KB
#define OFF_R16  0x40000     // r16[i][m] fp16: 256KB
#define OFF_BITS 0x80000     // bits[b][16] u64: 1MB
#define OFF_LR   0x180000    // lrT[m][t] bf16: 256KB
#define OFF_WC   0x1C0000    // wc16[p][m] fp16 (p=0..511): 128KB
#define OFF_U3   0x1E0000    // u316[p][m] fp16: 128KB
#define OFF_RQ   0x200000    // Rq[c][b][m] fp16: 32MB
#define OFF_T    0x2200000   // T[b] int32: 32KB

#define PACK_BLK (B_N * L_N / 256)   // 32768
#define EPS_BLK  32
#define ZERO_BLK 32

__device__ __forceinline__ unsigned short f32_bf16(float f) {
    union { float f; unsigned u; } x; x.f = f;
    unsigned u = x.u + 0x7FFFu + ((x.u >> 16) & 1u);   // RNE
    return (unsigned short)(u >> 16);
}

__device__ __forceinline__ float fdot2(h2 a, h2 b, float c) {
#if __has_builtin(__builtin_amdgcn_fdot2)
    return __builtin_amdgcn_fdot2(a, b, c, false);
#else
    return (float)a[0] * (float)b[0] + (float)a[1] * (float)b[1] + c;
#endif
}

// ---- K0: fused prep: spin-pack | eps tables (fp16 + pair tables) | zero -
__global__ __launch_bounds__(256) void k_prep(const int* __restrict__ inp,
        const float* __restrict__ eps, u64* __restrict__ bits,
        _Float16* __restrict__ w16, _Float16* __restrict__ r16,
        _Float16* __restrict__ wc16, _Float16* __restrict__ u316,
        unsigned short* __restrict__ lrT, float* __restrict__ out) {
    int bid = blockIdx.x;
    if (bid < PACK_BLK) {
        int g = bid * 256 + threadIdx.x;
        int v = inp[g];
        u64 m = __ballot(v != 0);
        if ((threadIdx.x & 63) == 0) bits[g >> 6] = m;   // word = b*16 + c
        return;
    }
    bid -= PACK_BLK;
    if (bid < EPS_BLK) {
        int wid = threadIdx.x >> 6, lane = threadIdx.x & 63;
        int m = bid * 4 + wid;
        const float* e0 = eps + (size_t)m * L_N + lane * 16;
        const float* e1 = eps + (size_t)(M_N + m) * L_N + lane * 16;
        float a[16], b[16];
        #pragma unroll
        for (int j = 0; j < 16; j += 4) {
            *(float4*)&a[j] = *(const float4*)&e0[j];
            *(float4*)&b[j] = *(const float4*)&e1[j];
        }
        float local = 1.f;
        #pragma unroll
        for (int j = 0; j < 16; ++j) local *= a[j];
        float sc = local;
        #pragma unroll
        for (int d = 1; d < 64; d <<= 1) {
            float up = __shfl_up(sc, d);
            if (lane >= d) sc *= up;
        }
        float prev = __shfl_up(sc, 1);
        float E = (lane == 0) ? 1.f : prev;
        int i0 = lane * 16;
        float rat0 = 1.f;
        #pragma unroll
        for (int j = 0; j < 16; ++j) {
            float rat = b[j] / a[j];
            float wval = E * (a[j] - b[j]);
            w16[(size_t)(i0 + j) * M_N + m] = (_Float16)wval;
            r16[(size_t)(i0 + j) * M_N + m] = (_Float16)rat;
            lrT[(size_t)m * L_N + i0 + j] = f32_bf16(__log2f(rat));
            if (j & 1) {
                int p = (i0 + j) >> 1;
                wc16[(size_t)p * M_N + m] = (_Float16)(wval * (rat0 - 1.f));
                u316[(size_t)p * M_N + m] = (_Float16)(rat0 * rat);
            } else {
                rat0 = rat;
            }
            E *= a[j];
        }
        return;
    }
    bid -= EPS_BLK;
    if (bid < ZERO_BLK) {
        out[bid * 256 + threadIdx.x] = 0.f;
    }
}

// ---- K2: MFMA chunk log-sums + f32 cumsum + exp2 -> fp16 excl prefix ----
// blocks [0,1024): prefix; blocks [1024,1056): per-b saturation step T.
__global__ __launch_bounds__(256) void k_slog2(const u64* __restrict__ bits,
        const unsigned short* __restrict__ lrT, _Float16* __restrict__ Rq,
        int* __restrict__ T) {
    if (blockIdx.x >= 1024) {
        int b = (blockIdx.x - 1024) * 256 + threadIdx.x;
        const u64* brow = bits + (size_t)b * 16;
        int n1 = 0, n0 = 0, Tv = 1024;
        for (int wd = 0; wd < 16; ++wd) {
            u64 x = brow[wd];
            int pc = __popcll(x);
            if (n1 + pc < HALF_N && n0 + (64 - pc) < HALF_N) {
                n1 += pc; n0 += 64 - pc;
                continue;
            }
            int found = 0;
            for (int k = 0; k < 64; ++k) {
                if (n1 >= HALF_N || n0 >= HALF_N) { Tv = wd * 64 + k; found = 1; break; }
                int sb = (int)((x >> k) & 1);
                n1 += sb; n0 += 1 - sb;
            }
            if (!found) Tv = (wd + 1) * 64;
            break;
        }
        T[b] = Tv;
        return;
    }
    int btile = blockIdx.x >> 1;
    int half = blockIdx.x & 1;
    int wid = threadIdx.x >> 6, lane = threadIdx.x & 63;
    int col = lane & 15, quad = lane >> 4;
    int m = (half * 4 + wid) * 16 + col;
    int b_row = btile * 16 + col;
    const u64* brow = bits + (size_t)b_row * 16;
    const unsigned short* lrow = lrT + (size_t)m * L_N;

    f32x4 cum = (f32x4){0.f, 0.f, 0.f, 0.f};

    for (int c = 0; c < C_N; ++c) {
        #pragma unroll
        for (int reg = 0; reg < 4; ++reg) {
            int b = btile * 16 + quad * 4 + reg;
            Rq[((size_t)c * B_N + b) * M_N + m] = (_Float16)exp2f(cum[reg]);
        }
        u64 wv = brow[c];
        short8 a0, a1;
        #pragma unroll
        for (int j = 0; j < 8; ++j) {
            a0[j] = (short)((((wv >> (quad * 8 + j)) & 1) != 0) ? 0x3F80 : 0);
            a1[j] = (short)((((wv >> (32 + quad * 8 + j)) & 1) != 0) ? 0x3F80 : 0);
        }
        const unsigned short* bp = lrow + c * 64 + quad * 8;
        union { uint4 u; short8 s; } bf0, bf1;
        bf0.u = *(const uint4*)bp;
        bf1.u = *(const uint4*)(bp + 32);
        cum = __builtin_amdgcn_mfma_f32_16x16x32_bf16(a0, bf0.s, cum, 0, 0, 0);
        cum = __builtin_amdgcn_mfma_f32_16x16x32_bf16(a1, bf1.s, cum, 0, 0, 0);
    }
}

// ------- K3: main loop, PAIRED steps (fp16), 8-lane groups, NB=4 ---------
// Per pair (t0,t1): D_t0 = sum wA*R; D_t1 = sum (wB + b0*wC)*R with
// wC = w[t1]*(r[t0]-1); single update R *= {1,r0,r1,r0r1}[b0+2b1].
__global__ __launch_bounds__(256) void k_main(const u64* __restrict__ bits,
        const _Float16* __restrict__ w16, const _Float16* __restrict__ r16,
        const _Float16* __restrict__ wc16, const _Float16* __restrict__ u316,
        const _Float16* __restrict__ Rq, const int* __restrict__ T,
        float* __restrict__ out) {
    __shared__ _Float16 wbuf[CH_N * M_N];        // 16KB
    __shared__ _Float16 rbuf[CH_N * M_N];        // 16KB
    __shared__ _Float16 wcbuf[(CH_N / 2) * M_N]; // 8KB
    __shared__ _Float16 u3buf[(CH_N / 2) * M_N]; // 8KB
    int c = blockIdx.x & (C_N - 1);
    int bblk = blockIdx.x >> 4;
    int lane = threadIdx.x & 63, wid = threadIdx.x >> 6;
    int s = lane & 7, g = lane >> 3;
    int b0i = bblk * 128 + wid * 32 + g * 4;
    int b_own = b0i + (s & 3);

    // stage chunk tables (all coalesced uint4)
    {
        const uint4* sw = (const uint4*)(w16 + (size_t)c * CH_N * M_N);
        const uint4* sr = (const uint4*)(r16 + (size_t)c * CH_N * M_N);
        const uint4* sc_ = (const uint4*)(wc16 + (size_t)c * (CH_N / 2) * M_N);
        const uint4* su = (const uint4*)(u316 + (size_t)c * (CH_N / 2) * M_N);
        uint4* dw = (uint4*)wbuf; uint4* dr = (uint4*)rbuf;
        uint4* dc = (uint4*)wcbuf; uint4* du = (uint4*)u3buf;
        #pragma unroll
        for (int t = 0; t < 4; ++t) {
            dw[threadIdx.x + t * 256] = sw[threadIdx.x + t * 256];
            dr[threadIdx.x + t * 256] = sr[threadIdx.x + t * 256];
        }
        #pragma unroll
        for (int t = 0; t < 2; ++t) {
            dc[threadIdx.x + t * 256] = sc_[threadIdx.x + t * 256];
            du[threadIdx.x + t * 256] = su[threadIdx.x + t * 256];
        }
    }

    // prefix load: fp16 Rq. R2[nb][j] = pair (m = s*16+2j)
    h2 R2[4][8];
    #pragma unroll
    for (int nb = 0; nb < 4; ++nb) {
        union { uint4 q[2]; h2 h[8]; } P;
        const uint4* src = (const uint4*)(Rq + ((size_t)c * B_N + (b0i + nb)) * M_N + s * 16);
        P.q[0] = src[0]; P.q[1] = src[1];
        #pragma unroll
        for (int j = 0; j < 8; ++j) R2[nb][j] = P.h[j];
    }
    int Tb = T[b_own];
    u64 wb[4];
    #pragma unroll
    for (int nb = 0; nb < 4; ++nb) wb[nb] = bits[(size_t)(b0i + nb) * 16 + c];

    __syncthreads();

    float sum = 0.f;
    #pragma unroll
    for (int h = 0; h < 2; ++h) {
        uint32 wh[4];
        #pragma unroll
        for (int nb = 0; nb < 4; ++nb) wh[nb] = (uint32)(wb[nb] >> (h * 32));
        uint32 owa = (s & 1) ? wh[1] : wh[0];
        uint32 owb = (s & 1) ? wh[3] : wh[2];
        uint32 ow = (s & 2) ? owb : owa;

        int rel = Tb - (c * CH_N + h * 32);
        uint32 vmask = (rel <= 0) ? 0u : ((rel >= 32) ? 0xFFFFFFFFu : ((1u << rel) - 1u));

        for (int pp = 0; pp < 16; ++pp) {
            int tt0 = 2 * pp;              // within half
            int rowi = h * 32 + tt0;       // within chunk
            int prow = h * 16 + pp;        // pair row within chunk
            union { uint4 q[2]; h2 h[8]; } W0, W1, WC;
            {
                const uint4* p0 = (const uint4*)&wbuf[rowi * M_N + s * 16];
                W0.q[0] = p0[0]; W0.q[1] = p0[1];
                const uint4* p1 = (const uint4*)&wbuf[(rowi + 1) * M_N + s * 16];
                W1.q[0] = p1[0]; W1.q[1] = p1[1];
                const uint4* pc = (const uint4*)&wcbuf[prow * M_N + s * 16];
                WC.q[0] = pc[0]; WC.q[1] = pc[1];
            }

            float pA[4], pD1[4];
            #pragma unroll
            for (int nb = 0; nb < 4; ++nb) {
                float aA = 0.f, aB = 0.f, aC = 0.f;
                #pragma unroll
                for (int j = 0; j < 8; ++j) {
                    aA = fdot2(R2[nb][j], W0.h[j], aA);
                    aB = fdot2(R2[nb][j], W1.h[j], aB);
                    aC = fdot2(R2[nb][j], WC.h[j], aC);
                }
                int bitn = (wh[nb] >> tt0) & 1;
                float bc = aB + aC;
                pA[nb] = aA;
                pD1[nb] = bitn ? bc : aB;
            }
            // swap-reduce both (each: lane s ends with value for b0i+(s&3))
            float DA, D1;
            {
                float xa = (s & 1) ? pA[1] : pA[0];
                float ya = (s & 1) ? pA[0] : pA[1];
                xa += __shfl_xor(ya, 1);
                float xb = (s & 1) ? pA[3] : pA[2];
                float yb = (s & 1) ? pA[2] : pA[3];
                xb += __shfl_xor(yb, 1);
                float u2 = (s & 2) ? xb : xa;
                float v2 = (s & 2) ? xa : xb;
                u2 += __shfl_xor(v2, 2);
                u2 += __shfl_xor(u2, 4);
                DA = u2;
            }
            {
                float xa = (s & 1) ? pD1[1] : pD1[0];
                float ya = (s & 1) ? pD1[0] : pD1[1];
                xa += __shfl_xor(ya, 1);
                float xb = (s & 1) ? pD1[3] : pD1[2];
                float yb = (s & 1) ? pD1[2] : pD1[3];
                xb += __shfl_xor(yb, 1);
                float u2 = (s & 2) ? xb : xa;
                float v2 = (s & 2) ? xa : xb;
                u2 += __shfl_xor(v2, 2);
                u2 += __shfl_xor(u2, 4);
                D1 = u2;
            }

            int s0 = (ow >> tt0) & 1;
            int s1 = (ow >> (tt0 + 1)) & 1;
            float y0 = s0 ? DA : -DA;
            float y1 = s1 ? D1 : -D1;
            float c0 = -0.5f * __logf(1.f + __expf(2.f * y0));
            float c1 = -0.5f * __logf(1.f + __expf(2.f * y1));
            sum += ((vmask >> tt0) & 1) ? c0 : 0.f;
            sum += ((vmask >> (tt0 + 1)) & 1) ? c1 : 0.f;

            // single paired update: v = b0 + 2*b1 selects {-,r0,r1,r0r1}
            #pragma unroll
            for (int nb = 0; nb < 4; ++nb) {
                int v = (int)((wh[nb] >> tt0) & 3u);
                if (v) {
                    const _Float16* src = (v == 3)
                        ? &u3buf[prow * M_N + s * 16]
                        : &rbuf[(rowi + (v >> 1)) * M_N + s * 16];
                    union { uint4 q[2]; h2 h[8]; } U;
                    U.q[0] = *(const uint4*)src;
                    U.q[1] = *((const uint4*)src + 1);
                    #pragma unroll
                    for (int j = 0; j < 8; ++j) R2[nb][j] *= U.h[j];
                }
            }
        }
    }
    if (s < 4) atomicAdd(&out[b_own], sum);
}

extern "C" void kernel_launch(void* const* d_in, const int* in_sizes, int n_in,
                              void* d_out, int out_size, void* d_ws, size_t ws_size,
                              hipStream_t stream) {
    const int*   inputs  = (const int*)d_in[0];     // (B, L) int32
    const float* epsilon = (const float*)d_in[1];   // (D, M, L) f32
    float* out = (float*)d_out;                     // (B,) f32

    char* ws = (char*)d_ws;
    _Float16* w16 = (_Float16*)(ws + OFF_W16);
    _Float16* r16 = (_Float16*)(ws + OFF_R16);
    u64*   bits   = (u64*)  (ws + OFF_BITS);
    unsigned short* lrT = (unsigned short*)(ws + OFF_LR);
    _Float16* wc16 = (_Float16*)(ws + OFF_WC);
    _Float16* u316 = (_Float16*)(ws + OFF_U3);
    _Float16* Rq  = (_Float16*)(ws + OFF_RQ);
    int*   T      = (int*)  (ws + OFF_T);

    k_prep<<<PACK_BLK + EPS_BLK + ZERO_BLK, 256, 0, stream>>>(
        inputs, epsilon, bits, w16, r16, wc16, u316, lrT, out);
    k_slog2<<<1024 + 32, 256, 0, stream>>>(bits, lrT, Rq, T);
    k_main<<<(B_N / 128) * C_N, 256, 0, stream>>>(bits, w16, r16, wc16, u316, Rq, T, out);
}

// Round 14
// 181.632 us; speedup vs baseline: 1.0859x; 1.0859x over previous
//
#include <hip/hip_runtime.h>
#include <hip/hip_fp16.h>

typedef unsigned long long u64;
typedef unsigned int uint32;
typedef short short8 __attribute__((ext_vector_type(8)));
typedef float f32x4 __attribute__((ext_vector_type(4)));
typedef _Float16 h2 __attribute__((ext_vector_type(2)));

#define B_N 8192
#define L_N 1024
#define M_N 128
#define C_N 16         // chunks over L
#define CH_N 64        // steps per chunk
#define HALF_N 512

// ws layout (bytes)
#define OFF_W16  0           // w16[i][m] fp16: 256KB
#define OFF_R16  0x40000     // r16[i][m] fp16: 256KB
#define OFF_BITS 0x80000     // bits[b][16] u64: 1MB
#define OFF_LR   0x180000    // lrT[m][t] bf16: 256KB
#define OFF_RQ   0x1C0000    // Rq[c][b][m] fp16: 32MB
#define OFF_T    0x21C0000   // T[b] int32: 32KB

#define PACK_BLK (B_N * L_N / 256)   // 32768
#define EPS_BLK  32
#define ZERO_BLK 32

__device__ __forceinline__ unsigned short f32_bf16(float f) {
    union { float f; unsigned u; } x; x.f = f;
    unsigned u = x.u + 0x7FFFu + ((x.u >> 16) & 1u);   // RNE
    return (unsigned short)(u >> 16);
}

__device__ __forceinline__ float fdot2(h2 a, h2 b, float c) {
#if __has_builtin(__builtin_amdgcn_fdot2)
    return __builtin_amdgcn_fdot2(a, b, c, false);
#else
    return (float)a[0] * (float)b[0] + (float)a[1] * (float)b[1] + c;
#endif
}

union HU { uint32 u; __half2 hh; h2 v2; };

// ---- K0: fused prep: spin-pack | eps tables (fp16) | zero out -----------
__global__ __launch_bounds__(256) void k_prep(const int* __restrict__ inp,
        const float* __restrict__ eps, u64* __restrict__ bits,
        _Float16* __restrict__ w16, _Float16* __restrict__ r16,
        unsigned short* __restrict__ lrT, float* __restrict__ out) {
    int bid = blockIdx.x;
    if (bid < PACK_BLK) {
        int g = bid * 256 + threadIdx.x;
        int v = inp[g];
        u64 m = __ballot(v != 0);
        if ((threadIdx.x & 63) == 0) bits[g >> 6] = m;   // word = b*16 + c
        return;
    }
    bid -= PACK_BLK;
    if (bid < EPS_BLK) {
        int wid = threadIdx.x >> 6, lane = threadIdx.x & 63;
        int m = bid * 4 + wid;
        const float* e0 = eps + (size_t)m * L_N + lane * 16;
        const float* e1 = eps + (size_t)(M_N + m) * L_N + lane * 16;
        float a[16], b[16];
        #pragma unroll
        for (int j = 0; j < 16; j += 4) {
            *(float4*)&a[j] = *(const float4*)&e0[j];
            *(float4*)&b[j] = *(const float4*)&e1[j];
        }
        float local = 1.f;
        #pragma unroll
        for (int j = 0; j < 16; ++j) local *= a[j];
        float sc = local;
        #pragma unroll
        for (int d = 1; d < 64; d <<= 1) {
            float up = __shfl_up(sc, d);
            if (lane >= d) sc *= up;
        }
        float prev = __shfl_up(sc, 1);
        float E = (lane == 0) ? 1.f : prev;
        int i0 = lane * 16;
        #pragma unroll
        for (int j = 0; j < 16; ++j) {
            float rat = b[j] / a[j];
            w16[(size_t)(i0 + j) * M_N + m] = (_Float16)(E * (a[j] - b[j]));
            r16[(size_t)(i0 + j) * M_N + m] = (_Float16)rat;
            lrT[(size_t)m * L_N + i0 + j] = f32_bf16(__log2f(rat));
            E *= a[j];
        }
        return;
    }
    bid -= EPS_BLK;
    if (bid < ZERO_BLK) {
        out[bid * 256 + threadIdx.x] = 0.f;
    }
}

// ---- K2: MFMA chunk log-sums + f32 cumsum + exp2 -> fp16 excl prefix ----
// blocks [0,1024): prefix; blocks [1024,1056): per-b saturation step T.
__global__ __launch_bounds__(256) void k_slog2(const u64* __restrict__ bits,
        const unsigned short* __restrict__ lrT, _Float16* __restrict__ Rq,
        int* __restrict__ T) {
    if (blockIdx.x >= 1024) {
        int b = (blockIdx.x - 1024) * 256 + threadIdx.x;
        const u64* brow = bits + (size_t)b * 16;
        int n1 = 0, n0 = 0, Tv = 1024;
        for (int wd = 0; wd < 16; ++wd) {
            u64 x = brow[wd];
            int pc = __popcll(x);
            if (n1 + pc < HALF_N && n0 + (64 - pc) < HALF_N) {
                n1 += pc; n0 += 64 - pc;
                continue;
            }
            int found = 0;
            for (int k = 0; k < 64; ++k) {
                if (n1 >= HALF_N || n0 >= HALF_N) { Tv = wd * 64 + k; found = 1; break; }
                int sb = (int)((x >> k) & 1);
                n1 += sb; n0 += 1 - sb;
            }
            if (!found) Tv = (wd + 1) * 64;
            break;
        }
        T[b] = Tv;
        return;
    }
    int btile = blockIdx.x >> 1;
    int half = blockIdx.x & 1;
    int wid = threadIdx.x >> 6, lane = threadIdx.x & 63;
    int col = lane & 15, quad = lane >> 4;
    int m = (half * 4 + wid) * 16 + col;
    int b_row = btile * 16 + col;
    const u64* brow = bits + (size_t)b_row * 16;
    const unsigned short* lrow = lrT + (size_t)m * L_N;

    f32x4 cum = (f32x4){0.f, 0.f, 0.f, 0.f};

    for (int c = 0; c < C_N; ++c) {
        #pragma unroll
        for (int reg = 0; reg < 4; ++reg) {
            int b = btile * 16 + quad * 4 + reg;
            Rq[((size_t)c * B_N + b) * M_N + m] = (_Float16)exp2f(cum[reg]);
        }
        u64 wv = brow[c];
        short8 a0, a1;
        #pragma unroll
        for (int j = 0; j < 8; ++j) {
            a0[j] = (short)((((wv >> (quad * 8 + j)) & 1) != 0) ? 0x3F80 : 0);
            a1[j] = (short)((((wv >> (32 + quad * 8 + j)) & 1) != 0) ? 0x3F80 : 0);
        }
        const unsigned short* bp = lrow + c * 64 + quad * 8;
        union { uint4 u; short8 s; } bf0, bf1;
        bf0.u = *(const uint4*)bp;
        bf1.u = *(const uint4*)(bp + 32);
        cum = __builtin_amdgcn_mfma_f32_16x16x32_bf16(a0, bf0.s, cum, 0, 0, 0);
        cum = __builtin_amdgcn_mfma_f32_16x16x32_bf16(a1, bf1.s, cum, 0, 0, 0);
    }
}

// ------- K3: main loop (R10 structure, guaranteed-packed fp16 ops) -------
__global__ __launch_bounds__(256, 2) void k_main(const u64* __restrict__ bits,
        const _Float16* __restrict__ w16, const _Float16* __restrict__ r16,
        const _Float16* __restrict__ Rq, const int* __restrict__ T,
        float* __restrict__ out) {
    __shared__ _Float16 wbuf[CH_N * M_N];   // 16KB
    __shared__ _Float16 rbuf[CH_N * M_N];   // 16KB
    int c = blockIdx.x & (C_N - 1);
    int bblk = blockIdx.x >> 4;
    int lane = threadIdx.x & 63, wid = threadIdx.x >> 6;
    int s = lane & 7, g = lane >> 3;
    int b0 = bblk * 128 + wid * 32 + g * 4;
    int b_own = b0 + (s & 3);

    // stage full chunk (16KB per table, coalesced uint4)
    {
        const uint4* sw = (const uint4*)(w16 + (size_t)c * CH_N * M_N);
        const uint4* sr = (const uint4*)(r16 + (size_t)c * CH_N * M_N);
        uint4* dw = (uint4*)wbuf; uint4* dr = (uint4*)rbuf;
        #pragma unroll
        for (int t = 0; t < 4; ++t) {
            dw[threadIdx.x + t * 256] = sw[threadIdx.x + t * 256];
            dr[threadIdx.x + t * 256] = sr[threadIdx.x + t * 256];
        }
    }

    // prefix load: fp16 Rq. R2[nb][j] = packed pair (m = s*16+2j)
    HU R2[4][8];
    #pragma unroll
    for (int nb = 0; nb < 4; ++nb) {
        union { uint4 q[2]; uint32 w[8]; } P;
        const uint4* src = (const uint4*)(Rq + ((size_t)c * B_N + (b0 + nb)) * M_N + s * 16);
        P.q[0] = src[0]; P.q[1] = src[1];
        #pragma unroll
        for (int j = 0; j < 8; ++j) R2[nb][j].u = P.w[j];
    }
    int Tb = T[b_own];
    u64 wb[4];
    #pragma unroll
    for (int nb = 0; nb < 4; ++nb) wb[nb] = bits[(size_t)(b0 + nb) * 16 + c];

    __syncthreads();

    const uint32 ONE2 = 0x3C003C00u;   // packed fp16 {1,1}
    const float LOG2E2 = 2.885390082f; // 2*log2(e)
    const float NHL2 = -0.3465735903f; // -0.5*ln2
    float sum = 0.f;
    #pragma unroll
    for (int h = 0; h < 2; ++h) {
        uint32 wh[4];
        #pragma unroll
        for (int nb = 0; nb < 4; ++nb) wh[nb] = (uint32)(wb[nb] >> (h * 32));
        uint32 owa = (s & 1) ? wh[1] : wh[0];
        uint32 owb = (s & 1) ? wh[3] : wh[2];
        uint32 ow = (s & 2) ? owb : owa;

        int rel = Tb - (c * CH_N + h * 32);
        uint32 vmask = (rel <= 0) ? 0u : ((rel >= 32) ? 0xFFFFFFFFu : ((1u << rel) - 1u));

        for (int tt = 0; tt < 32; ++tt) {
            int base = (h * 32 + tt) * M_N + s * 16;
            union { uint4 q[2]; uint32 w[8]; h2 v2[8]; } W;
            union { uint4 q[2]; uint32 w[8]; } Rr;
            W.q[0] = *(const uint4*)&wbuf[base];
            W.q[1] = *((const uint4*)&wbuf[base] + 1);
            Rr.q[0] = *(const uint4*)&rbuf[base];
            Rr.q[1] = *((const uint4*)&rbuf[base] + 1);

            float d[4];
            #pragma unroll
            for (int nb = 0; nb < 4; ++nb) {
                float acc = 0.f;
                #pragma unroll
                for (int j = 0; j < 8; ++j) acc = fdot2(R2[nb][j].v2, W.v2[j], acc);
                d[nb] = acc;
            }
            // swap-reduce: lane s ends with D for b0 + (s&3)
            float xa = (s & 1) ? d[1] : d[0];
            float ya = (s & 1) ? d[0] : d[1];
            xa += __shfl_xor(ya, 1);
            float xb = (s & 1) ? d[3] : d[2];
            float yb = (s & 1) ? d[2] : d[3];
            xb += __shfl_xor(yb, 1);
            float u2 = (s & 2) ? xb : xa;
            float v2 = (s & 2) ? xa : xb;
            u2 += __shfl_xor(v2, 2);
            u2 += __shfl_xor(u2, 4);
            float Dv = u2;

            // softplus in native exp2/log2: -0.5*ln2 * log2(1 + 2^(2*log2e*y))
            int sbit = (ow >> tt) & 1;
            float y = sbit ? Dv : -Dv;
            float contr = NHL2 * __log2f(1.f + exp2f(LOG2E2 * y));
            sum += ((vmask >> tt) & 1) ? contr : 0.f;

            // guaranteed-packed update: 32-bit select + v_pk_mul_f16
            #pragma unroll
            for (int nb = 0; nb < 4; ++nb) {
                bool bit = (wh[nb] >> tt) & 1;
                #pragma unroll
                for (int j = 0; j < 8; ++j) {
                    HU sel; sel.u = bit ? Rr.w[j] : ONE2;
                    R2[nb][j].hh = __hmul2(R2[nb][j].hh, sel.hh);
                }
            }
        }
    }
    if (s < 4) atomicAdd(&out[b_own], sum);
}

extern "C" void kernel_launch(void* const* d_in, const int* in_sizes, int n_in,
                              void* d_out, int out_size, void* d_ws, size_t ws_size,
                              hipStream_t stream) {
    const int*   inputs  = (const int*)d_in[0];     // (B, L) int32
    const float* epsilon = (const float*)d_in[1];   // (D, M, L) f32
    float* out = (float*)d_out;                     // (B,) f32

    char* ws = (char*)d_ws;
    _Float16* w16 = (_Float16*)(ws + OFF_W16);
    _Float16* r16 = (_Float16*)(ws + OFF_R16);
    u64*   bits   = (u64*)  (ws + OFF_BITS);
    unsigned short* lrT = (unsigned short*)(ws + OFF_LR);
    _Float16* Rq  = (_Float16*)(ws + OFF_RQ);
    int*   T      = (int*)  (ws + OFF_T);

    k_prep<<<PACK_BLK + EPS_BLK + ZERO_BLK, 256, 0, stream>>>(
        inputs, epsilon, bits, w16, r16, lrT, out);
    k_slog2<<<1024 + 32, 256, 0, stream>>>(bits, lrT, Rq, T);
    k_main<<<(B_N / 128) * C_N, 256, 0, stream>>>(bits, w16, r16, Rq, T, out);
}